// Round 2
// 283.451 us; speedup vs baseline: 1.1699x; 1.1699x over previous
//
#include <hip/hip_runtime.h>

// PWC-Net 9x9 correlation — LDS-staged, double-buffered version (r2: fix
// first-tile staging source to be per-lane; r1 passed a wave-uniform source
// so every lane loaded the same 16B -> wrong F tile, absmax 0.73).
//
// Theory: the direct-register kernel (205us/dispatch) was L2-path bound:
// VALUBusy 15%, HBM 8.8%, 3840 cyc/channel vs 144 cyc of FMA issue. Each wave
// issued 6 global 16B loads at 32B lane stride per channel (~72KB/CU/channel
// of L2->L1 traffic, ~2x sector overfetch, latency-exposed).
// This version stages first[8][192] and second[8][192] (rows for this block's
// dy) into LDS once per (block, channel) via global_load_lds (lane-contiguous
// 16B -> full sector efficiency, no VGPR roundtrip), double-buffered so the
// stage of channel c+1 overlaps the 72 FMAs of channel c. Compute reads LDS
// (ds_read_b128, 16B-aligned).
//
// OOB handling (fully uniform, no per-channel masking VALU):
//  - rows ys outside [0,H): per-lane staging *source* pointer selects a
//    zeroed __device__ row with stride 0 -> LDS rows are zero -> acc = 0.
//  - x window halo beyond [0,W): thread-constant LDS pointers select a 16B
//    zeroed LDS pad (same trick as the g_zeros version).
//
// Numerics identical to the 331us kernel (same fmaf order, same scale).

namespace {
constexpr int kC = 128;
constexpr int kH = 112;
constexpr int kW = 192;
constexpr int kD = 4;            // max displacement
constexpr int kKD = 9;           // 2*kD+1
constexpr int kHW = kH * kW;     // 21504
constexpr long long kCHW = (long long)kC * kHW;

constexpr int PX = 8;            // pixels per thread along x
constexpr int XG = kW / PX;      // 24 x-groups
constexpr int YT = 8;            // rows per block
constexpr int NT = XG * YT;      // 192 threads = 3 waves
constexpr int TILE = YT * kW;    // 1536 floats per staged channel tile
}  // namespace

// 768B of zeros: staging source for out-of-image second rows.
__device__ __attribute__((aligned(16))) float g_zero_row[kW] = {};

typedef const __attribute__((address_space(1))) void* gas_ptr;
typedef __attribute__((address_space(3))) void* las_ptr;

__device__ __forceinline__ void gload16(const float* g, float* l) {
  __builtin_amdgcn_global_load_lds((gas_ptr)g, (las_ptr)l, 16, 0, 0);
}

__global__ __launch_bounds__(NT, 4)
void corr81_kernel(const float* __restrict__ first,
                   const float* __restrict__ second,
                   float* __restrict__ out) {
  __shared__ __align__(16) float zpad[4];        // x-halo zeros (never staged over)
  __shared__ __align__(16) float Sb[2][TILE];    // second tiles (double buffer)
  __shared__ __align__(16) float Fb[2][TILE];    // first tiles  (double buffer)

  const int g = blockIdx.x;
  const int b = g & 7;             // batch -> XCD slab
  const int i = g >> 3;
  const int dy = i % kKD;          // dy innermost -> L2 sliding window
  const int y0 = (i / kKD) * YT;

  const int tid = threadIdx.x;
  const int xg = tid % XG;
  const int yl = tid / XG;
  const int px0 = xg * PX;
  const int ys0 = y0 + dy - kD;    // first staged second-row (may be OOB)

  if (tid == 0) { zpad[0] = 0.f; zpad[1] = 0.f; zpad[2] = 0.f; zpad[3] = 0.f; }

  // ---- staging source pointers (per lane, computed once) ----
  // first tile: rows y0..y0+7 are 1536 contiguous floats, always in-bounds.
  // Lane handles floats [tid*4, tid*4+4) and [(tid+NT)*4, ...).
  const float* fsrc = first + (long long)b * kCHW + (long long)y0 * kW +
                      (long long)tid * 4;
  // second tile: 2 issues of 192 lanes x 16B; lane pos -> row pos/48.
  const float* ssrc[2];
  long long sstr[2];
#pragma unroll
  for (int j = 0; j < 2; ++j) {
    const int pos = j * NT + tid;          // 0..383
    const int r = pos / 48;                // staged row 0..7
    const int col4 = (pos - r * 48) * 4;   // float offset within row
    const int ysr = ys0 + r;
    const bool inb = (unsigned)ysr < (unsigned)kH;
    ssrc[j] = inb ? (second + (long long)b * kCHW + (long long)ysr * kW + col4)
                  : (g_zero_row + col4);
    sstr[j] = inb ? (long long)kHW : 0ll;
  }

  float acc[PX][kKD];
#pragma unroll
  for (int p = 0; p < PX; ++p)
#pragma unroll
    for (int d = 0; d < kKD; ++d) acc[p][d] = 0.0f;

  // issue 4 x global_load_lds (12KB) for one channel into buffer P, advance
  auto stage = [&](int P) {
    gload16(fsrc,            &Fb[P][tid * 4]);
    gload16(fsrc + NT * 4,   &Fb[P][tid * 4 + NT * 4]);
    gload16(ssrc[0],         &Sb[P][tid * 4]);
    gload16(ssrc[1],         &Sb[P][tid * 4 + NT * 4]);
    fsrc += kHW;
    ssrc[0] += sstr[0];
    ssrc[1] += sstr[1];
  };

  // 6 x ds_read_b128 + 72 FMA from buffer P
  auto compute = [&](int P) {
    const float* fp = &Fb[P][yl * kW + px0];
    const float* s1 = &Sb[P][yl * kW + px0];
    const float* w0p = (xg == 0) ? zpad : (s1 - 4);       // window [-4,0)
    const float* w3p = (xg == XG - 1) ? zpad : (s1 + 8);  // window [12,16)
    const float4 f0 = *(const float4*)(fp);
    const float4 f1 = *(const float4*)(fp + 4);
    const float4 w0 = *(const float4*)(w0p);
    const float4 w1 = *(const float4*)(s1);
    const float4 w2 = *(const float4*)(s1 + 4);
    const float4 w3 = *(const float4*)(w3p);

    const float fa[PX] = {f0.x, f0.y, f0.z, f0.w, f1.x, f1.y, f1.z, f1.w};
    const float sw[16] = {w0.x, w0.y, w0.z, w0.w, w1.x, w1.y, w1.z, w1.w,
                          w2.x, w2.y, w2.z, w2.w, w3.x, w3.y, w3.z, w3.w};
#pragma unroll
    for (int p = 0; p < PX; ++p)
#pragma unroll
      for (int d = 0; d < kKD; ++d)
        acc[p][d] = fmaf(fa[p], sw[p + d], acc[p][d]);
  };

  // ---- software-pipelined channel loop (unroll 2: compile-time parity) ----
  stage(0);             // c = 0
  __syncthreads();      // drains vmcnt -> buf0 ready
  for (int c = 0; c < kC; c += 2) {
    stage(1);                         // c+1 (always < kC)
    compute(0);                       // channel c
    __syncthreads();                  // buf1 ready; buf0 consumed
    if (c + 2 < kC) stage(0);         // c+2
    compute(1);                       // channel c+1
    __syncthreads();                  // buf0 ready; buf1 consumed
  }

  // epilogue: 9 dx channels x 8 px, coalesced dwordx4 stores
  const float scale = 1.0f / (float)kC;
  float* obase = out + ((long long)b * 81 + (long long)dy * kKD) * kHW +
                 (long long)(y0 + yl) * kW + px0;
#pragma unroll
  for (int d = 0; d < kKD; ++d) {
    float4 o0 = make_float4(acc[0][d] * scale, acc[1][d] * scale,
                            acc[2][d] * scale, acc[3][d] * scale);
    float4 o1 = make_float4(acc[4][d] * scale, acc[5][d] * scale,
                            acc[6][d] * scale, acc[7][d] * scale);
    float* op = obase + (long long)d * kHW;
    *(float4*)op = o0;
    *(float4*)(op + 4) = o1;
  }
}

extern "C" void kernel_launch(void* const* d_in, const int* in_sizes, int n_in,
                              void* d_out, int out_size, void* d_ws, size_t ws_size,
                              hipStream_t stream) {
  const float* first = (const float*)d_in[0];
  const float* second = (const float*)d_in[1];
  float* out = (float*)d_out;

  const int grid = 8 * (kH / YT) * kKD;  // 8 * 14 * 9 = 1008 blocks
  corr81_kernel<<<grid, NT, 0, stream>>>(first, second, out);
}